// Round 14
// baseline (116.930 us; speedup 1.0000x reference)
//
#include <hip/hip_runtime.h>

#define NT 32768
#define DI 36
#define HH 64
#define G3 192
#define LH 20
#define SGS 196            // Sg row stride (floats); 196%32=4 -> 2-way b128 (free)

#define NLOG2E -1.4426950408889634f   // r/z pre-scale: sigmoid(x)=rcp(1+exp2(-x*log2e))
#define TLOG2E 2.8853900817779268f    // n pre-scale: tanh(x)=1-2*rcp(1+exp2(2x*log2e))

// shared memory map (bytes) — total 32544; 5 blocks x 32544 = 159.1KB < 160KB
//   [0, 27440)        Sg: float[35][196] gi slice; reused as Hid for MLP
//   [27440, 32480)    union (disjoint lifetimes):
//                       EmbP ushort[35][72] (hi-pass then lo-pass staging)
//                       Hb ushort[2][1152]  (h-hi exchange, dbl-buffered)
//                       HfH/HfL ushort[16][72] x2 (final h for MLP1)
//   [32480, 32544)    sfirst[16]
#define UNION_OFF  27440
#define SFIRST_OFF 32480
#define SMEM_BYTES 32544

typedef __attribute__((ext_vector_type(8))) short bf16x8;
typedef __attribute__((ext_vector_type(4))) float f32x4;
typedef __attribute__((ext_vector_type(4))) int int4v;
union frag_cast { int4v i4; bf16x8 h8; };

__device__ __forceinline__ unsigned f2u(float f) { union { float f; unsigned u; } x; x.f = f; return x.u; }
__device__ __forceinline__ float u2f(unsigned u) { union { float f; unsigned u; } x; x.u = u; return x.f; }
__device__ __forceinline__ unsigned short f2bf_rne(float f) {
    union { float f; unsigned u; } x; x.f = f;
    unsigned r = x.u + 0x7FFFu + ((x.u >> 16) & 1u);
    return (unsigned short)(r >> 16);
}

// Prep: pre-packed A-fragments (unchanged from R12).
// frags 0..23: W_ih hi (trunc, scaled) | 24..47: W_ih lo | 48..71: W_hh hi (RNE, scaled)
// frags 72..79: W1 hi (trunc) | 80..87: W1 lo
// A-frag convention (verified R3): lane l holds A[m=16mt+(l&15)][k=32kt+8(l>>4)+jj].
__global__ __launch_bounds__(64) void prep_kernel(
    const float* __restrict__ W_ih, const float* __restrict__ W_hh,
    const float* __restrict__ W1, int4v* __restrict__ wfrag)
{
    const int b = (int)blockIdx.x;         // 0..87
    const int l = (int)threadIdx.x;
    unsigned short e[8];
    if (b < 72) {
        const int set = b / 24, fb = b % 24;
        const int mt = fb >> 1, kt = fb & 1;
        const int m = mt * 16 + (l & 15);  // j row 0..191
        const float sc = ((mt >> 2) < 2) ? NLOG2E : TLOG2E;
        const int k0 = kt * 32 + (l >> 4) * 8;
#pragma unroll
        for (int jj = 0; jj < 8; ++jj) {
            const int k = k0 + jj;
            if (set == 2) {
                e[jj] = f2bf_rne(W_hh[(size_t)m * HH + k] * sc);
            } else {
                const float v = (k < DI) ? W_ih[(size_t)m * DI + k] * sc : 0.f;
                const unsigned u = f2u(v);
                if (set == 0) e[jj] = (unsigned short)(u >> 16);   // trunc hi
                else          e[jj] = (unsigned short)(f2u(v - u2f(u & 0xFFFF0000u)) >> 16);
            }
        }
    } else {
        const int bb = b - 72;             // 0..15
        const bool is_lo = bb >= 8;
        const int f = bb & 7;
        const int mt = f >> 1, kt = f & 1;
        const int m = mt * 16 + (l & 15);  // 0..63
        const int k0 = kt * 32 + (l >> 4) * 8;
#pragma unroll
        for (int jj = 0; jj < 8; ++jj) {
            const float v = W1[(size_t)m * HH + k0 + jj];
            const unsigned u = f2u(v);
            if (!is_lo) e[jj] = (unsigned short)(u >> 16);         // trunc hi
            else        e[jj] = (unsigned short)(f2u(v - u2f(u & 0xFFFF0000u)) >> 16);
        }
    }
    int4v p;
    p.x = e[0] | ((unsigned)e[1] << 16); p.y = e[2] | ((unsigned)e[3] << 16);
    p.z = e[4] | ((unsigned)e[5] << 16); p.w = e[6] | ((unsigned)e[7] << 16);
    wfrag[b * 64 + l] = p;
}

// Fused kernel: 2048 blocks x 256 thr (4 waves), 16 timesteps/block.
// Phase 1: gi-GEMM in TWO passes over one zeroed Emb plane (hi then lo),
//   partials parked in Sg between passes. B-frag rows CLAMPED to <35 (R13's
//   OOB LDS reads past the allocation memviol'd the dispatch).
// Phase 2: recurrence (h-hi via MFMA, 6 MFMA + 2 b128/step, 1 barrier/step).
// Phase 3: MLP1 via MFMA, MLP2 scalar.
__global__ __launch_bounds__(256, 5) void gru_kernel(
    const float* __restrict__ emb, const int4v* __restrict__ wfrag,
    const float* __restrict__ b_ih, const float* __restrict__ b_hh,
    const float* __restrict__ b1, const float* __restrict__ W2,
    const float* __restrict__ b2, const int* __restrict__ dones,
    float* __restrict__ out)
{
    __shared__ __align__(16) char SMEM[SMEM_BYTES];
    float* const Sg = (float*)SMEM;
    unsigned short* const EmbP = (unsigned short*)(SMEM + UNION_OFF);  // [35][72]
    unsigned short* const HbB  = (unsigned short*)(SMEM + UNION_OFF);  // [2][1152]
    unsigned short* const HfH  = (unsigned short*)(SMEM + UNION_OFF);  // [16][72]
    unsigned short* const HfL  = HfH + 1152;
    int* const sfirst = (int*)(SMEM + SFIRST_OFF);

    const int tid = threadIdx.x;
    const int lane = tid & 63;
    const int W = tid >> 6;          // wave id = j-quarter owner
    const int li = lane & 15;        // t within group (MFMA col)
    const int q = lane >> 4;         // quad
    const int blk = ((int)blockIdx.x & 7) * 256 + ((int)blockIdx.x >> 3);
    const int T0 = blk * 16;

    // ---- Phase 0: emb window -> registers; zero EmbP; window starts ----
    float ev[5];
#pragma unroll
    for (int k = 0; k < 5; ++k) {
        const int i = tid + 256 * k;
        if (i < 35 * DI) {
            const int r = i / DI, c = i % DI;
            int tt = T0 - (LH - 1) + r; tt = tt < 0 ? 0 : tt;
            ev[k] = emb[(size_t)tt * DI + c];
        }
    }
    {   // zero EmbP: 35*72 ushorts = 5040 B = 315 int4v (k>=36 cols stay 0)
        int4v* z = (int4v*)EmbP;
        for (int i = tid; i < 315; i += 256) z[i] = int4v{0, 0, 0, 0};
    }
    if (tid < 16) {                  // window start: dones[t-19..t-1] only
        const int tt = T0 + tid;
        int lo = tt - (LH - 1); if (lo < 0) lo = 0;
        int ws = lo;
        for (int j = lo; j < tt; ++j)
            ws = (dones[j] != 0) ? (j + 1) : ws;
        sfirst[tid] = ws - (tt - (LH - 1));
    }
    __syncthreads();                 // zero-fill complete
    // stage HI plane (cols 0..35 only; 36..71 remain zero)
#pragma unroll
    for (int k = 0; k < 5; ++k) {
        const int i = tid + 256 * k;
        if (i < 35 * DI)
            EmbP[(i / DI) * 72 + (i % DI)] = (unsigned short)(f2u(ev[k]) >> 16);
    }

    // W_ih fragments (dead after Phase 1 -> VGPR headroom for 5 waves/SIMD)
    bf16x8 aih[3][2], ail[3][2];
#pragma unroll
    for (int g = 0; g < 3; ++g)
#pragma unroll
        for (int kt = 0; kt < 2; ++kt) {
            const int fb = (4 * g + W) * 2 + kt;
            frag_cast a, b;
            a.i4 = wfrag[(0 * 24 + fb) * 64 + lane];
            b.i4 = wfrag[(1 * 24 + fb) * 64 + lane];
            aih[g][kt] = a.h8; ail[g][kt] = b.h8;
        }

    const int joff = 16 * W + 4 * q; // this thread's j' base within each gate
    f32x4 biasI[3];                  // gi-GEMM acc init = (b_ih + b_hh_rz) * sc
#pragma unroll
    for (int g = 0; g < 3; ++g) {
        const float sc = (g < 2) ? NLOG2E : TLOG2E;
        const f32x4 bi = *(const f32x4*)&b_ih[64 * g + joff];
        if (g < 2) {
            const f32x4 bh = *(const f32x4*)&b_hh[64 * g + joff];
#pragma unroll
            for (int rr = 0; rr < 4; ++rr) biasI[g][rr] = (bi[rr] + bh[rr]) * sc;
        } else {
#pragma unroll
            for (int rr = 0; rr < 4; ++rr) biasI[g][rr] = bi[rr] * sc;
        }
    }
    __syncthreads();                 // HI plane staged

    // ---- Phase 1a: hi-pass (aih+ail x ebh), partials -> Sg ----
#pragma unroll
    for (int nt = 0; nt < 3; ++nt) {
        const int row = 16 * nt + li;
        const int rowr = row < 35 ? row : 34;   // CLAMPED read (no OOB; discarded)
        bf16x8 ebh[2];
#pragma unroll
        for (int kt = 0; kt < 2; ++kt)
            ebh[kt] = *(const bf16x8*)&EmbP[rowr * 72 + 32 * kt + 8 * q];
#pragma unroll
        for (int g = 0; g < 3; ++g) {
            f32x4 a = biasI[g];
            a = __builtin_amdgcn_mfma_f32_16x16x32_bf16(aih[g][0], ebh[0], a, 0, 0, 0);
            a = __builtin_amdgcn_mfma_f32_16x16x32_bf16(aih[g][1], ebh[1], a, 0, 0, 0);
            a = __builtin_amdgcn_mfma_f32_16x16x32_bf16(ail[g][0], ebh[0], a, 0, 0, 0);
            a = __builtin_amdgcn_mfma_f32_16x16x32_bf16(ail[g][1], ebh[1], a, 0, 0, 0);
            if (row < 35)
                *(f32x4*)&Sg[row * SGS + 64 * g + joff] = a;
        }
    }
    __syncthreads();                 // all hi-pass reads done
    // stage LO plane (same buffer, from registers; cols 36..71 still zero)
#pragma unroll
    for (int k = 0; k < 5; ++k) {
        const int i = tid + 256 * k;
        if (i < 35 * DI) {
            const unsigned u = f2u(ev[k]);
            EmbP[(i / DI) * 72 + (i % DI)] =
                (unsigned short)(f2u(ev[k] - u2f(u & 0xFFFF0000u)) >> 16);
        }
    }
    __syncthreads();                 // LO plane staged

    // ---- Phase 1b: lo-pass (aih x ebl), accumulate onto Sg partials ----
#pragma unroll
    for (int nt = 0; nt < 3; ++nt) {
        const int row = 16 * nt + li;
        const int rowr = row < 35 ? row : 34;   // clamped read row
        bf16x8 ebl[2];
#pragma unroll
        for (int kt = 0; kt < 2; ++kt)
            ebl[kt] = *(const bf16x8*)&EmbP[rowr * 72 + 32 * kt + 8 * q];
#pragma unroll
        for (int g = 0; g < 3; ++g) {
            f32x4 a = *(const f32x4*)&Sg[rowr * SGS + 64 * g + joff];  // clamped C
            a = __builtin_amdgcn_mfma_f32_16x16x32_bf16(aih[g][0], ebl[0], a, 0, 0, 0);
            a = __builtin_amdgcn_mfma_f32_16x16x32_bf16(aih[g][1], ebl[1], a, 0, 0, 0);
            if (row < 35)
                *(f32x4*)&Sg[row * SGS + 64 * g + joff] = a;
        }
    }
    __syncthreads();                 // Emb dead; Hb (alias) live from here
    const int sfr = sfirst[li];

    // W_hh fragments (loaded late to cap peak VGPR)
    bf16x8 whh[3][2];
#pragma unroll
    for (int g = 0; g < 3; ++g)
#pragma unroll
        for (int kt = 0; kt < 2; ++kt) {
            frag_cast c; c.i4 = wfrag[(48 + (4 * g + W) * 2 + kt) * 64 + lane];
            whh[g][kt] = c.h8;
        }
    f32x4 bnv;                       // n-gate step init = 2*log2e * b_hh_n
    {
        const f32x4 b = *(const f32x4*)&b_hh[128 + joff];
#pragma unroll
        for (int rr = 0; rr < 4; ++rr) bnv[rr] = b[rr] * TLOG2E;
    }

    // ---- Phase 2: recurrence (h-hi only through MFMA) ----
    float h[4] = {0.f, 0.f, 0.f, 0.f};
    f32x4 accR, accZ, accN, ginv;
    f32x4 gvR, gvZ, gvN;             // LDS->reg prefetch for step s+1

    {   // s = 0 (h=0: no MFMA), writes buf1 for s=1
        const float* gp = Sg + li * SGS;
        accR = *(const f32x4*)(gp + joff);
        accZ = *(const f32x4*)(gp + 64 + joff);
        ginv = *(const f32x4*)(gp + 128 + joff);
        accN = bnv;
        const bool valid = (0 >= sfr);
#pragma unroll
        for (int rr = 0; rr < 4; ++rr) {
            const float r  = __builtin_amdgcn_rcpf(1.f + __builtin_amdgcn_exp2f(accR[rr]));
            const float z  = __builtin_amdgcn_rcpf(1.f + __builtin_amdgcn_exp2f(accZ[rr]));
            const float nc = 1.f - 2.f * __builtin_amdgcn_rcpf(1.f + __builtin_amdgcn_exp2f(ginv[rr] + r * accN[rr]));
            h[rr] = valid ? fmaf(z, 0.f - nc, nc) : 0.f;
        }
        uint2 ph;
        ph.x = __builtin_amdgcn_perm(f2u(h[1]), f2u(h[0]), 0x07060302u);
        ph.y = __builtin_amdgcn_perm(f2u(h[3]), f2u(h[2]), 0x07060302u);
        *(uint2*)&HbB[1152 + li * 72 + joff] = ph;
        // prefetch gi for s=1
        const float* gq = Sg + (li + 1) * SGS;
        gvR = *(const f32x4*)(gq + joff);
        gvZ = *(const f32x4*)(gq + 64 + joff);
        gvN = *(const f32x4*)(gq + 128 + joff);
    }
    __syncthreads();

#pragma unroll 2
    for (int s = 1; s < LH; ++s) {
        const int rb = s & 1;        // read buffer; write buffer = 1-rb
        const bf16x8 bh0 = *(const bf16x8*)&HbB[rb * 1152 + li * 72 + 8 * q];
        const bf16x8 bh1 = *(const bf16x8*)&HbB[rb * 1152 + li * 72 + 32 + 8 * q];

        accR = gvR; accZ = gvZ; ginv = gvN; accN = bnv;
        {   // prefetch s+1's gi (row clamped; s=19 value unused)
            int r = li + s + 1; r = r > 34 ? 34 : r;
            const float* gq = Sg + r * SGS;
            gvR = *(const f32x4*)(gq + joff);
            gvZ = *(const f32x4*)(gq + 64 + joff);
            gvN = *(const f32x4*)(gq + 128 + joff);
        }
#pragma unroll
        for (int g = 0; g < 3; ++g) {
            f32x4 a = (g == 0) ? accR : (g == 1) ? accZ : accN;
            a = __builtin_amdgcn_mfma_f32_16x16x32_bf16(whh[g][0], bh0, a, 0, 0, 0);
            a = __builtin_amdgcn_mfma_f32_16x16x32_bf16(whh[g][1], bh1, a, 0, 0, 0);
            if (g == 0) accR = a; else if (g == 1) accZ = a; else accN = a;
        }
        const bool valid = (s >= sfr);
#pragma unroll
        for (int rr = 0; rr < 4; ++rr) {
            const float r  = __builtin_amdgcn_rcpf(1.f + __builtin_amdgcn_exp2f(accR[rr]));
            const float z  = __builtin_amdgcn_rcpf(1.f + __builtin_amdgcn_exp2f(accZ[rr]));
            const float nc = 1.f - 2.f * __builtin_amdgcn_rcpf(1.f + __builtin_amdgcn_exp2f(ginv[rr] + r * accN[rr]));
            const float hn = fmaf(z, h[rr] - nc, nc);
            h[rr] = valid ? hn : h[rr];
        }
        if (s != LH - 1) {
            uint2 ph;
            ph.x = __builtin_amdgcn_perm(f2u(h[1]), f2u(h[0]), 0x07060302u);
            ph.y = __builtin_amdgcn_perm(f2u(h[3]), f2u(h[2]), 0x07060302u);
            *(uint2*)&HbB[(1 - rb) * 1152 + li * 72 + joff] = ph;
        }
        __syncthreads();             // LDS-only drain (cheap)
    }

    // ---- Phase 3: MLP. Final h -> hi/lo planes (exact), MLP1 via MFMA ----
    {
        const unsigned u0 = f2u(h[0]), u1 = f2u(h[1]);
        const unsigned u2 = f2u(h[2]), u3 = f2u(h[3]);
        uint2 ph, pl;
        ph.x = __builtin_amdgcn_perm(u1, u0, 0x07060302u);
        ph.y = __builtin_amdgcn_perm(u3, u2, 0x07060302u);
        const unsigned l0 = f2u(h[0] - u2f(u0 & 0xFFFF0000u));
        const unsigned l1 = f2u(h[1] - u2f(u1 & 0xFFFF0000u));
        const unsigned l2 = f2u(h[2] - u2f(u2 & 0xFFFF0000u));
        const unsigned l3 = f2u(h[3] - u2f(u3 & 0xFFFF0000u));
        pl.x = __builtin_amdgcn_perm(l1, l0, 0x07060302u);
        pl.y = __builtin_amdgcn_perm(l3, l2, 0x07060302u);
        *(uint2*)&HfH[li * 72 + joff] = ph;
        *(uint2*)&HfL[li * 72 + joff] = pl;
    }
    __syncthreads();
    {   // MLP1: wave W computes hid[m=16W+4q+rr][t=li] via 6 MFMA
        bf16x8 w1h[2], w1l[2];
#pragma unroll
        for (int kt = 0; kt < 2; ++kt) {
            frag_cast a, b;
            a.i4 = wfrag[(72 + W * 2 + kt) * 64 + lane];
            b.i4 = wfrag[(80 + W * 2 + kt) * 64 + lane];
            w1h[kt] = a.h8; w1l[kt] = b.h8;
        }
        const bf16x8 bh0 = *(const bf16x8*)&HfH[li * 72 + 8 * q];
        const bf16x8 bh1 = *(const bf16x8*)&HfH[li * 72 + 32 + 8 * q];
        const bf16x8 bl0 = *(const bf16x8*)&HfL[li * 72 + 8 * q];
        const bf16x8 bl1 = *(const bf16x8*)&HfL[li * 72 + 32 + 8 * q];
        f32x4 a = *(const f32x4*)&b1[joff];
        a = __builtin_amdgcn_mfma_f32_16x16x32_bf16(w1h[0], bh0, a, 0, 0, 0);
        a = __builtin_amdgcn_mfma_f32_16x16x32_bf16(w1h[1], bh1, a, 0, 0, 0);
        a = __builtin_amdgcn_mfma_f32_16x16x32_bf16(w1l[0], bh0, a, 0, 0, 0);
        a = __builtin_amdgcn_mfma_f32_16x16x32_bf16(w1l[1], bh1, a, 0, 0, 0);
        a = __builtin_amdgcn_mfma_f32_16x16x32_bf16(w1h[0], bl0, a, 0, 0, 0);
        a = __builtin_amdgcn_mfma_f32_16x16x32_bf16(w1h[1], bl1, a, 0, 0, 0);
        __syncthreads();             // HfH/HfL reads done before Sg reuse below
        float4 st;
        st.x = fmaxf(a[0], 0.f); st.y = fmaxf(a[1], 0.f);
        st.z = fmaxf(a[2], 0.f); st.w = fmaxf(a[3], 0.f);
        *(float4*)&Sg[li * 68 + joff] = st;      // Hid[t][m] stride 68
    }
    __syncthreads();
    if (tid < 64) {                  // MLP2: thread (tid>>2 -> t, tid&3 -> c)
        const int tt = tid >> 2, c = tid & 3;
        float o2 = b2[c];
        for (int m4 = 0; m4 < 16; ++m4) {
            const float4 hv = *(const float4*)&Sg[tt * 68 + 4 * m4];
            const float4 wv = *(const float4*)&W2[c * HH + 4 * m4];
            o2 += hv.x * wv.x + hv.y * wv.y + hv.z * wv.z + hv.w * wv.w;
        }
        out[(size_t)(T0 + tt) * 4 + c] = o2;     // 256B contiguous
    }
}

extern "C" void kernel_launch(void* const* d_in, const int* in_sizes, int n_in,
                              void* d_out, int out_size, void* d_ws, size_t ws_size,
                              hipStream_t stream) {
    const float* emb  = (const float*)d_in[0];
    const float* W_ih = (const float*)d_in[1];
    const float* W_hh = (const float*)d_in[2];
    const float* b_ih = (const float*)d_in[3];
    const float* b_hh = (const float*)d_in[4];
    const float* W1   = (const float*)d_in[5];
    const float* b1   = (const float*)d_in[6];
    const float* W2   = (const float*)d_in[7];
    const float* b2   = (const float*)d_in[8];
    const int*   dn   = (const int*)d_in[9];

    int4v* wfrag = (int4v*)d_ws;     // 88 frags x 64 lanes x 16B = 90 KB
    float* o = (float*)d_out;

    prep_kernel<<<88, 64, 0, stream>>>(W_ih, W_hh, W1, wfrag);
    gru_kernel<<<NT / 16, 256, 0, stream>>>(emb, wfrag, b_ih, b_hh,
                                            b1, W2, b2, dn, o);
}